// Round 11
// baseline (134.081 us; speedup 1.0000x reference)
//
#include <hip/hip_runtime.h>
#include <math.h>

typedef unsigned short u16;
typedef unsigned int   u32;

#define B_       64
#define NN_      64
#define HL_      50
#define IN_DIM   384
#define POS_DIM  64
#define ATT_DIM  256
#define NEWS_DIM 448   // IN_DIM + POS_DIM

typedef __attribute__((ext_vector_type(8))) short short8;   // bf16x8 MFMA frag
typedef __attribute__((ext_vector_type(4))) float f32x4;    // MFMA acc

#if __has_builtin(__builtin_amdgcn_exp2f)
#define EXP2F(x) __builtin_amdgcn_exp2f(x)
#else
#define EXP2F(x) exp2f(x)
#endif
#if __has_builtin(__builtin_amdgcn_rcpf)
#define RCPF(x) __builtin_amdgcn_rcpf(x)
#else
#define RCPF(x) (1.0f/(x))
#endif

__device__ __forceinline__ float bf2f(u16 u) {
    union { u32 i; float f; } v; v.i = ((u32)u) << 16; return v.f;
}
// Pack 8 f32 -> 8 bf16 (RNE) via v_cvt_pk_bf16_f32 (gfx950; learn_hip
// m214v22-verified). Same rounding as the old f2bf path -> MFMA inputs
// value-identical to the prep-converted pipeline.
__device__ __forceinline__ short8 cvt8(float4 a, float4 b) {
    union { short8 s; u32 u[4]; } r;
    asm("v_cvt_pk_bf16_f32 %0, %1, %2" : "=v"(r.u[0]) : "v"(a.x), "v"(a.y));
    asm("v_cvt_pk_bf16_f32 %0, %1, %2" : "=v"(r.u[1]) : "v"(a.z), "v"(a.w));
    asm("v_cvt_pk_bf16_f32 %0, %1, %2" : "=v"(r.u[2]) : "v"(b.x), "v"(b.y));
    asm("v_cvt_pk_bf16_f32 %0, %1, %2" : "=v"(r.u[3]) : "v"(b.z), "v"(b.w));
    return r.s;
}
// tanh(x) = 1 - 2/(1+2^(x*2*log2e)); v_exp+v_rcp saturate correctly at +-inf.
__device__ __forceinline__ float fast_tanh(float x) {
    float e = EXP2F(x * 2.88539008f);
    return 1.0f - 2.0f * RCPF(1.0f + e);
}

// ---------------- K1: fused NT GEMMs + nf writer. R21: prep dispatch
// ELIMINATED. bf16 conversion happens inline at fragment build (cvt8,
// value-identical RNE); A reads come straight from newsv/logv/pos f32;
// W fragments from W1 f32. Redundant f32 re-reads are L2-resident
// (~2-3us extra) vs ~13us saved (prep time + dispatch boundary).
// bid < 1824: R4-proven 16x64 tiles, XCD-aligned (1824 = 8*228).
// bid >= 1824: 1024 nf-writer blocks (d_out, no consumer, no dependency).
__global__ __launch_bounds__(64) void gemm_k(
    const float* __restrict__ newsv, const float* __restrict__ logv,
    const float* __restrict__ pos, const float* __restrict__ W1,
    const float* __restrict__ b1,
    float* __restrict__ pn, float* __restrict__ plT, float* __restrict__ nf)
{
    int bid = blockIdx.x;
    int lane = threadIdx.x;
    if (bid >= 1824) {             // ---- nf writer: rows 4j..4j+3 ----
        int j = bid - 1824;        // [0,1024)
#pragma unroll
        for (int t = 0; t < 7; t++) {
            int idx  = t * 64 + lane;          // [0,448)
            int row4 = idx / 112, col4 = idx - row4 * 112;
            int r    = j * 4 + row4;
            float4 v = (col4 < 96)
                ? *(const float4*)(newsv + (size_t)r * IN_DIM + col4 * 4)
                : make_float4(0.f, 0.f, 0.f, 0.f);
            *(float4*)(nf + (size_t)r * NEWS_DIM + col4 * 4) = v;
        }
        return;
    }

    int m = lane & 15, q = lane >> 4;
    int x = bid & 7, j = bid >> 3; // j in [0,228)
    bool is_pn = j < 128;
    int r0, c0, koff, klen;
    if (is_pn) {                   // 16 tiles per b: 4 row-bands x 4 col-tiles
        int b = x * 8 + (j >> 4);
        r0 = b * 64 + ((j >> 2) & 3) * 16;
        c0 = (j & 3) * 64;
        koff = 0;        klen = IN_DIM;
    } else {                       // 100 tiles: 25 row-bands x 4 col-tiles
        int j2 = j - 128;
        r0 = 400 * x + (j2 >> 2) * 16;
        c0 = (j2 & 3) * 64;
        koff = NEWS_DIM; klen = NEWS_DIM;
    }

    int row = r0 + m;
    // A source: pn -> newsv row; pl -> logv row (e<384) / pos row (e>=384).
    // Both pointers pre-offset by q*8 so (ptr + k) = element q*8+k.
    const float* Af;
    const float* Ap2 = nullptr;
    if (is_pn) {
        Af = newsv + (size_t)row * IN_DIM + q * 8;
    } else {
        int hh = row % 50;
        Af  = logv + (size_t)row * IN_DIM + q * 8;
        Ap2 = pos + (size_t)(1 + hh) * POS_DIM - IN_DIM + q * 8;
    }
    const float* Wp = W1 + (size_t)(c0 + m) * (2 * NEWS_DIM) + koff + q * 8;

    f32x4 acc[4];
#pragma unroll
    for (int b = 0; b < 4; b++) acc[b] = (f32x4){0.f, 0.f, 0.f, 0.f};

    for (int k = 0; k < klen; k += 32) {
        int e0 = q * 8 + k;        // fragment of 8 never straddles 384
        const float* as = (!is_pn && e0 >= IN_DIM) ? Ap2 : Af;
        short8 af = cvt8(*(const float4*)(as + k), *(const float4*)(as + k + 4));
        short8 wf[4];
#pragma unroll
        for (int ct = 0; ct < 4; ct++) {
            const float* ws_ = Wp + (size_t)ct * 16 * (2 * NEWS_DIM);
            wf[ct] = cvt8(*(const float4*)(ws_ + k), *(const float4*)(ws_ + k + 4));
        }
#pragma unroll
        for (int ct = 0; ct < 4; ct++)
            acc[ct] = __builtin_amdgcn_mfma_f32_16x16x32_bf16(af, wf[ct], acc[ct], 0, 0, 0);
    }
    // C/D layout: col = lane&15, row = (lane>>4)*4 + i  [m89]
#pragma unroll
    for (int ct = 0; ct < 4; ct++)
#pragma unroll
        for (int i = 0; i < 4; i++) {
            int gr = r0 + q * 4 + i;
            int gc = c0 + ct * 16 + m;
            float v = acc[ct][i];
            if (is_pn) {
                pn[(size_t)gr * ATT_DIM + gc] = v + b1[gc];
            } else {
                int bb = gr / HL_, hh = gr - bb * HL_;
                plT[(size_t)(bb * ATT_DIM + gc) * HL_ + hh] = v;
            }
        }
}

// ---------------- K2: FUSED logits -> masked softmax -> out = attn x lf.
// Phase 1: R10-proven (4x reuse + LDS-staged pl chunks, pipelined).
// Phase 2: R21 -- reads logv/pos f32 DIRECTLY (lf_bf gone). Same instr
// count (float2 vs u32), 2x bytes but L2-resident (~0.7MB/XCD), and
// numerics improve (reference computes attn x lf in f32).
__global__ __launch_bounds__(256) void attn_out_k(
    const float* __restrict__ pn, const float* __restrict__ plT,
    const float* __restrict__ w2, const int* __restrict__ lmask,
    const float* __restrict__ logv, const float* __restrict__ pos,
    float* __restrict__ out)
{
    __shared__ float pl_s[4][800];             // per-wave 16-a chunk  12.8KB
    __shared__ float part[4][4][64];           // [a-quarter][n][h]     4KB
    __shared__ float at4[64][4];               // [h][n] attn weights   1KB
    int lane = threadIdx.x & 63;
    int wid = __builtin_amdgcn_readfirstlane((int)(threadIdx.x >> 6)); // 0..3
    // XCD-clustered map: XCD x owns b in [8x,8x+8); 16 n-quads per b.
    int x     = blockIdx.x & 7;
    int local = blockIdx.x >> 3;               // [0,128)
    int b     = x * 8 + (local >> 4);
    int n0    = (local & 15) * 4;              // n-quad base
    int g0    = b * 64 + n0;                   // first of 4 pn/out rows
    int n_hl  = (lane < HL_) ? lane : (HL_ - 1);

    // ---- phase 1: a-range [64*wid, +64), 4 chunks of 16 a (800 f32) ----
    int a0 = wid * 64;
    const float* pr0 = pn + (size_t)(g0 + 0) * ATT_DIM + a0;  // uniform
    const float* pr1 = pn + (size_t)(g0 + 1) * ATT_DIM + a0;
    const float* pr2 = pn + (size_t)(g0 + 2) * ATT_DIM + a0;
    const float* pr3 = pn + (size_t)(g0 + 3) * ATT_DIM + a0;
    const float* w2o = w2 + a0;
    const float4* src4 = (const float4*)(plT + ((size_t)b * ATT_DIM + a0) * HL_);
    float* pls = pl_s[wid];

    float c0 = 0.f, c1 = 0.f, c2 = 0.f, c3 = 0.f;   // chain A per n
    float d0 = 0.f, d1 = 0.f, d2 = 0.f, d3 = 0.f;   // chain B per n

    // prologue: loads for chunk 0 (200 float4 per chunk)
    float4 s0 = src4[lane];
    float4 s1 = src4[lane + 64];
    float4 s2 = src4[lane + 128];
    float4 s3 = (lane < 8) ? src4[lane + 192] : make_float4(0.f, 0.f, 0.f, 0.f);

    for (int c = 0; c < 4; c++) {
        *(float4*)&pls[4 * lane]         = s0;
        *(float4*)&pls[4 * (lane + 64)]  = s1;
        *(float4*)&pls[4 * (lane + 128)] = s2;
        if (lane < 8) *(float4*)&pls[4 * (lane + 192)] = s3;
        if (c < 3) {
            const float4* nx = src4 + (c + 1) * 200;
            s0 = nx[lane];
            s1 = nx[lane + 64];
            s2 = nx[lane + 128];
            if (lane < 8) s3 = nx[lane + 192];
        }
        int ab = c * 16;
#pragma unroll 4
        for (int i = 0; i < 16; i += 4) {
            int a = ab + i;
            float4 w4 = *(const float4*)(w2o + a);      // uniform -> s_load
            float4 pA = *(const float4*)(pr0 + a);      // uniform -> s_load
            float4 pB = *(const float4*)(pr1 + a);
            float4 pC = *(const float4*)(pr2 + a);
            float4 pD = *(const float4*)(pr3 + a);
            float l0 = pls[(i + 0) * HL_ + n_hl];
            float l1 = pls[(i + 1) * HL_ + n_hl];
            float l2 = pls[(i + 2) * HL_ + n_hl];
            float l3 = pls[(i + 3) * HL_ + n_hl];
            c0 = __builtin_fmaf(fast_tanh(pA.x + l0), w4.x, c0);
            d0 = __builtin_fmaf(fast_tanh(pA.y + l1), w4.y, d0);
            c0 = __builtin_fmaf(fast_tanh(pA.z + l2), w4.z, c0);
            d0 = __builtin_fmaf(fast_tanh(pA.w + l3), w4.w, d0);
            c1 = __builtin_fmaf(fast_tanh(pB.x + l0), w4.x, c1);
            d1 = __builtin_fmaf(fast_tanh(pB.y + l1), w4.y, d1);
            c1 = __builtin_fmaf(fast_tanh(pB.z + l2), w4.z, c1);
            d1 = __builtin_fmaf(fast_tanh(pB.w + l3), w4.w, d1);
            c2 = __builtin_fmaf(fast_tanh(pC.x + l0), w4.x, c2);
            d2 = __builtin_fmaf(fast_tanh(pC.y + l1), w4.y, d2);
            c2 = __builtin_fmaf(fast_tanh(pC.z + l2), w4.z, c2);
            d2 = __builtin_fmaf(fast_tanh(pC.w + l3), w4.w, d2);
            c3 = __builtin_fmaf(fast_tanh(pD.x + l0), w4.x, c3);
            d3 = __builtin_fmaf(fast_tanh(pD.y + l1), w4.y, d3);
            c3 = __builtin_fmaf(fast_tanh(pD.z + l2), w4.z, c3);
            d3 = __builtin_fmaf(fast_tanh(pD.w + l3), w4.w, d3);
        }
    }
    part[wid][0][lane] = c0 + d0;
    part[wid][1][lane] = c1 + d1;
    part[wid][2][lane] = c2 + d2;
    part[wid][3][lane] = c3 + d3;
    __syncthreads();

    // ---- softmax: wave wid handles n = wid ----
    float acc = (part[0][wid][lane] + part[1][wid][lane])
              + (part[2][wid][lane] + part[3][wid][lane]);
    int mv = (lane < HL_) ? lmask[b * HL_ + lane] : 0;
    float logit = mv ? acc : -1e9f;            // b2 dropped: softmax-invariant
    float mx = logit;
#pragma unroll
    for (int o = 32; o > 0; o >>= 1) mx = fmaxf(mx, __shfl_xor(mx, o));
    float e = EXP2F((logit - mx) * 1.44269504f);   // masked lanes -> 0
    float s = e;
#pragma unroll
    for (int o = 32; o > 0; o >>= 1) s += __shfl_xor(s, o);
    at4[lane][wid] = e * RCPF(s);
    __syncthreads();

    // ---- phase 2: wave wid covers float-pair range [56*wid, +56), 4 n's ----
    // d-pair = (2k, 2k+1); 2k<384 -> logv, else pos (pair never straddles).
    // Only wave 3 mixes sources (per-lane cndmask on address).
    int l56 = (lane < 56) ? lane : 55;
    int k   = wid * 56 + l56;                  // [0,224)
    const float* lrow = logv + (size_t)b * (HL_ * IN_DIM) + 2 * k; // +h*384
    const float* prow = pos + POS_DIM + 2 * k - IN_DIM;            // +h*64
    bool usep = (k >= 192);
    float q00 = 0.f, q01 = 0.f, q10 = 0.f, q11 = 0.f;
    float q20 = 0.f, q21 = 0.f, q30 = 0.f, q31 = 0.f;
    for (int h = 0; h < HL_; h++) {
        float4 av = *(const float4*)at4[h];    // LDS broadcast, 4 attn vals
        float2 v = usep ? *(const float2*)(prow + h * POS_DIM)
                        : *(const float2*)(lrow + (size_t)h * IN_DIM);
        q00 = fmaf(av.x, v.x, q00);  q01 = fmaf(av.x, v.y, q01);
        q10 = fmaf(av.y, v.x, q10);  q11 = fmaf(av.y, v.y, q11);
        q20 = fmaf(av.z, v.x, q20);  q21 = fmaf(av.z, v.y, q21);
        q30 = fmaf(av.w, v.x, q30);  q31 = fmaf(av.w, v.y, q31);
    }
    if (lane < 56) {
        float* o0 = out + (size_t)g0 * NEWS_DIM + 2 * k;
        *(float2*)(o0)                = make_float2(q00, q01);
        *(float2*)(o0 + NEWS_DIM)     = make_float2(q10, q11);
        *(float2*)(o0 + 2 * NEWS_DIM) = make_float2(q20, q21);
        *(float2*)(o0 + 3 * NEWS_DIM) = make_float2(q30, q31);
    }
}

extern "C" void kernel_launch(void* const* d_in, const int* in_sizes, int n_in,
                              void* d_out, int out_size, void* d_ws, size_t ws_size,
                              hipStream_t stream) {
    const float* logv  = (const float*)d_in[0];  // (64,50,384) f32
    const int*   lmask = (const int*)d_in[1];    // (64,50) i32
    const float* newsv = (const float*)d_in[2];  // (64,64,384) f32
    const float* pos   = (const float*)d_in[3];  // (100,64) f32; row 0 == 0
    const float* W1    = (const float*)d_in[4];  // (256,896) f32
    const float* b1    = (const float*)d_in[5];  // (256,) f32
    const float* w2    = (const float*)d_in[6];  // (1,256) f32
    // b2 unused (softmax-invariant shift)

    float* out = (float*)d_out;                  // [user_log | nf], f32
    float* nf  = out + (size_t)B_ * NN_ * NEWS_DIM;

    // d_ws: only the two intermediates now.
    char* ws = (char*)d_ws;
    float* pn  = (float*)(ws + 0);               // 4096x256 f32  (4,194,304 B)
    float* plT = (float*)(ws + 4194304);         // 64x256x50 f32 (3,276,800 B)

    gemm_k    <<<2848, 64, 0, stream>>>(newsv, logv, pos, W1, b1, pn, plT, nf);
    attn_out_k<<<1024, 256, 0, stream>>>(pn, plT, w2, lmask, logv, pos, out);
}

// Round 12
// 122.336 us; speedup vs baseline: 1.0960x; 1.0960x over previous
//
#include <hip/hip_runtime.h>
#include <math.h>

typedef unsigned short u16;
typedef unsigned int   u32;

#define B_       64
#define NN_      64
#define HL_      50
#define IN_DIM   384
#define POS_DIM  64
#define ATT_DIM  256
#define NEWS_DIM 448   // IN_DIM + POS_DIM

typedef __attribute__((ext_vector_type(8))) short short8;   // bf16x8 MFMA frag
typedef __attribute__((ext_vector_type(4))) float f32x4;    // MFMA acc

#if __has_builtin(__builtin_amdgcn_exp2f)
#define EXP2F(x) __builtin_amdgcn_exp2f(x)
#else
#define EXP2F(x) exp2f(x)
#endif
#if __has_builtin(__builtin_amdgcn_rcpf)
#define RCPF(x) __builtin_amdgcn_rcpf(x)
#else
#define RCPF(x) (1.0f/(x))
#endif

__device__ __forceinline__ u16 f2bf(float f) {
    union { float f; u32 i; } v; v.f = f;
    u32 r = v.i + 0x7fffu + ((v.i >> 16) & 1u);   // RNE
    return (u16)(r >> 16);
}
__device__ __forceinline__ float bf2f(u16 u) {
    union { u32 i; float f; } v; v.i = ((u32)u) << 16; return v.f;
}
__device__ __forceinline__ uint2 pack4(float4 v) {
    return make_uint2((u32)f2bf(v.x) | ((u32)f2bf(v.y) << 16),
                      (u32)f2bf(v.z) | ((u32)f2bf(v.w) << 16));
}
// tanh(x) = 1 - 2/(1+2^(x*2*log2e)); v_exp+v_rcp saturate correctly at +-inf.
__device__ __forceinline__ float fast_tanh(float x) {
    float e = EXP2F(x * 2.88539008f);
    return 1.0f - 2.0f * RCPF(1.0f + e);
}

// ---------------- K0: bf16-convert W1/newsv/lf into ws; nf (f32) -> d_out.
// R4-proven XCD-aligned segments. NOTE (R11 lesson): this dispatch is
// amortization, not overhead -- W is re-read 28x by gemm's tiles; inline
// f32->bf16 conversion in gemm doubled its critical-loop loads (+15us).
__global__ __launch_bounds__(256) void prep_k(
    const float* __restrict__ W1, const float* __restrict__ newsv,
    const float* __restrict__ logv, const float* __restrict__ pos,
    u16* __restrict__ Wbf, u16* __restrict__ nv_bf, u16* __restrict__ lf_bf,
    float* __restrict__ nf)
{
    u32 bid = blockIdx.x, tid = threadIdx.x;
    if (bid < 2936u) {
        u32 x = bid & 7u, j = bid >> 3;
        if (j < 192u) {            // newsv rows [512x, 512x+512) -> nv_bf + nf
            u32 idx = j * 256u + tid;              // < 49152
            u32 r = 512u * x + idx / 96u, d4 = idx % 96u;
            float4 v = *(const float4*)(newsv + (size_t)r * IN_DIM + d4 * 4u);
            *(uint2*)(nv_bf + (size_t)r * IN_DIM + d4 * 4u) = pack4(v);
            *(float4*)(nf + (size_t)r * NEWS_DIM + d4 * 4u) = v;
        } else if (j < 342u) {     // logv rows [400x, 400x+400) -> lf_bf head
            u32 idx = (j - 192u) * 256u + tid;     // < 38400
            u32 r = 400u * x + idx / 96u, d4 = idx % 96u;
            float4 v = *(const float4*)(logv + (size_t)r * IN_DIM + d4 * 4u);
            *(uint2*)(lf_bf + (size_t)r * NEWS_DIM + d4 * 4u) = pack4(v);
        } else {                   // pos tail, lf rows [400x, 400x+400)
            u32 idx = (j - 342u) * 256u + tid;     // < 6400
            u32 r = 400u * x + idx / 16u, d4 = idx % 16u;
            u32 h = r % HL_;
            float4 v = *(const float4*)(pos + (size_t)(1u + h) * POS_DIM + d4 * 4u);
            *(uint2*)(lf_bf + (size_t)r * NEWS_DIM + IN_DIM + d4 * 4u) = pack4(v);
        }
        return;
    }
    bid -= 2936u;
    if (bid < 224u) {              // W1 -> Wbf (read-shared; placement moot)
        u32 i = bid * 256u + tid;
        float4 v = *(const float4*)(W1 + (size_t)i * 4u);
        *(uint2*)(Wbf + (size_t)i * 4u) = pack4(v);
        return;
    }
    bid -= 224u;
    {                              // nf zero tail (no downstream reader)
        u32 i = bid * 256u + tid;  // < 65536
        u32 r = i / 16u, d4 = i % 16u;
        *(float4*)(nf + (size_t)r * NEWS_DIM + IN_DIM + d4 * 4u) =
            make_float4(0.f, 0.f, 0.f, 0.f);
    }
}

// ---------------- K1: fused NT GEMMs, 16x64-per-wave tiles.
// BYTE-IDENTICAL to R4 (proven).
__global__ __launch_bounds__(64) void gemm_k(
    const u16* __restrict__ nv_bf, const u16* __restrict__ lf_bf,
    const u16* __restrict__ Wbf, const float* __restrict__ b1,
    float* __restrict__ pn, float* __restrict__ plT)
{
    int bid = blockIdx.x;          // 1824 = 8*228
    int lane = threadIdx.x;
    int m = lane & 15, q = lane >> 4;
    int x = bid & 7, j = bid >> 3; // j in [0,228)
    bool is_pn = j < 128;
    int r0, c0, lda, koff, klen;
    const u16* A;
    if (is_pn) {                   // 16 tiles per b: 4 row-bands x 4 col-tiles
        int b = x * 8 + (j >> 4);
        r0 = b * 64 + ((j >> 2) & 3) * 16;
        c0 = (j & 3) * 64;
        A = nv_bf; lda = IN_DIM;   koff = 0;        klen = IN_DIM;
    } else {                       // 100 tiles: 25 row-bands x 4 col-tiles
        int j2 = j - 128;
        r0 = 400 * x + (j2 >> 2) * 16;
        c0 = (j2 & 3) * 64;
        A = lf_bf; lda = NEWS_DIM; koff = NEWS_DIM; klen = NEWS_DIM;
    }

    f32x4 acc[4];
#pragma unroll
    for (int b = 0; b < 4; b++) acc[b] = (f32x4){0.f, 0.f, 0.f, 0.f};

    const u16* Ap = A + (size_t)(r0 + m) * lda + q * 8;
    const u16* Wp = Wbf + (size_t)(c0 + m) * (2 * NEWS_DIM) + koff + q * 8;

    for (int k = 0; k < klen; k += 32) {
        short8 af, wf[4];
        af = *(const short8*)(Ap + k);
#pragma unroll
        for (int ct = 0; ct < 4; ct++) wf[ct] = *(const short8*)(Wp + ct * 16 * (2 * NEWS_DIM) + k);
#pragma unroll
        for (int ct = 0; ct < 4; ct++)
            acc[ct] = __builtin_amdgcn_mfma_f32_16x16x32_bf16(af, wf[ct], acc[ct], 0, 0, 0);
    }
    // C/D layout: col = lane&15, row = (lane>>4)*4 + i  [m89]
#pragma unroll
    for (int ct = 0; ct < 4; ct++)
#pragma unroll
        for (int i = 0; i < 4; i++) {
            int gr = r0 + q * 4 + i;
            int gc = c0 + ct * 16 + m;
            float v = acc[ct][i];
            if (is_pn) {
                pn[(size_t)gr * ATT_DIM + gc] = v + b1[gc];
            } else {
                int bb = gr / HL_, hh = gr - bb * HL_;
                plT[(size_t)(bb * ATT_DIM + gc) * HL_ + hh] = v;
            }
        }
}

// ---------------- K2: FUSED logits -> masked softmax -> out = attn x lf.
// BYTE-IDENTICAL to R10 (4x reuse + LDS-staged pipelined pl chunks;
// session-best 123.5us configuration).
__global__ __launch_bounds__(256) void attn_out_k(
    const float* __restrict__ pn, const float* __restrict__ plT,
    const float* __restrict__ w2, const int* __restrict__ lmask,
    const u16* __restrict__ lf_bf, float* __restrict__ out)
{
    __shared__ float pl_s[4][800];             // per-wave 16-a chunk  12.8KB
    __shared__ float part[4][4][64];           // [a-quarter][n][h]     4KB
    __shared__ float at4[64][4];               // [h][n] attn weights   1KB
    int lane = threadIdx.x & 63;
    int wid = __builtin_amdgcn_readfirstlane((int)(threadIdx.x >> 6)); // 0..3
    // XCD-clustered map: XCD x owns b in [8x,8x+8); 16 n-quads per b.
    int x     = blockIdx.x & 7;
    int local = blockIdx.x >> 3;               // [0,128)
    int b     = x * 8 + (local >> 4);
    int n0    = (local & 15) * 4;              // n-quad base
    int g0    = b * 64 + n0;                   // first of 4 pn/out rows
    int n_hl  = (lane < HL_) ? lane : (HL_ - 1);

    // ---- phase 1: a-range [64*wid, +64), 4 chunks of 16 a (800 f32) ----
    int a0 = wid * 64;
    const float* pr0 = pn + (size_t)(g0 + 0) * ATT_DIM + a0;  // uniform
    const float* pr1 = pn + (size_t)(g0 + 1) * ATT_DIM + a0;
    const float* pr2 = pn + (size_t)(g0 + 2) * ATT_DIM + a0;
    const float* pr3 = pn + (size_t)(g0 + 3) * ATT_DIM + a0;
    const float* w2o = w2 + a0;
    const float4* src4 = (const float4*)(plT + ((size_t)b * ATT_DIM + a0) * HL_);
    float* pls = pl_s[wid];

    float c0 = 0.f, c1 = 0.f, c2 = 0.f, c3 = 0.f;   // chain A per n
    float d0 = 0.f, d1 = 0.f, d2 = 0.f, d3 = 0.f;   // chain B per n

    // prologue: loads for chunk 0 (200 float4 per chunk)
    float4 s0 = src4[lane];
    float4 s1 = src4[lane + 64];
    float4 s2 = src4[lane + 128];
    float4 s3 = (lane < 8) ? src4[lane + 192] : make_float4(0.f, 0.f, 0.f, 0.f);

    for (int c = 0; c < 4; c++) {
        *(float4*)&pls[4 * lane]         = s0;
        *(float4*)&pls[4 * (lane + 64)]  = s1;
        *(float4*)&pls[4 * (lane + 128)] = s2;
        if (lane < 8) *(float4*)&pls[4 * (lane + 192)] = s3;
        if (c < 3) {
            const float4* nx = src4 + (c + 1) * 200;
            s0 = nx[lane];
            s1 = nx[lane + 64];
            s2 = nx[lane + 128];
            if (lane < 8) s3 = nx[lane + 192];
        }
        int ab = c * 16;
#pragma unroll 4
        for (int i = 0; i < 16; i += 4) {
            int a = ab + i;
            float4 w4 = *(const float4*)(w2o + a);      // uniform -> s_load
            float4 pA = *(const float4*)(pr0 + a);      // uniform -> s_load
            float4 pB = *(const float4*)(pr1 + a);
            float4 pC = *(const float4*)(pr2 + a);
            float4 pD = *(const float4*)(pr3 + a);
            float l0 = pls[(i + 0) * HL_ + n_hl];
            float l1 = pls[(i + 1) * HL_ + n_hl];
            float l2 = pls[(i + 2) * HL_ + n_hl];
            float l3 = pls[(i + 3) * HL_ + n_hl];
            c0 = __builtin_fmaf(fast_tanh(pA.x + l0), w4.x, c0);
            d0 = __builtin_fmaf(fast_tanh(pA.y + l1), w4.y, d0);
            c0 = __builtin_fmaf(fast_tanh(pA.z + l2), w4.z, c0);
            d0 = __builtin_fmaf(fast_tanh(pA.w + l3), w4.w, d0);
            c1 = __builtin_fmaf(fast_tanh(pB.x + l0), w4.x, c1);
            d1 = __builtin_fmaf(fast_tanh(pB.y + l1), w4.y, d1);
            c1 = __builtin_fmaf(fast_tanh(pB.z + l2), w4.z, c1);
            d1 = __builtin_fmaf(fast_tanh(pB.w + l3), w4.w, d1);
            c2 = __builtin_fmaf(fast_tanh(pC.x + l0), w4.x, c2);
            d2 = __builtin_fmaf(fast_tanh(pC.y + l1), w4.y, d2);
            c2 = __builtin_fmaf(fast_tanh(pC.z + l2), w4.z, c2);
            d2 = __builtin_fmaf(fast_tanh(pC.w + l3), w4.w, d2);
            c3 = __builtin_fmaf(fast_tanh(pD.x + l0), w4.x, c3);
            d3 = __builtin_fmaf(fast_tanh(pD.y + l1), w4.y, d3);
            c3 = __builtin_fmaf(fast_tanh(pD.z + l2), w4.z, c3);
            d3 = __builtin_fmaf(fast_tanh(pD.w + l3), w4.w, d3);
        }
    }
    part[wid][0][lane] = c0 + d0;
    part[wid][1][lane] = c1 + d1;
    part[wid][2][lane] = c2 + d2;
    part[wid][3][lane] = c3 + d3;
    __syncthreads();

    // ---- softmax: wave wid handles n = wid ----
    float acc = (part[0][wid][lane] + part[1][wid][lane])
              + (part[2][wid][lane] + part[3][wid][lane]);
    int mv = (lane < HL_) ? lmask[b * HL_ + lane] : 0;
    float logit = mv ? acc : -1e9f;            // b2 dropped: softmax-invariant
    float mx = logit;
#pragma unroll
    for (int o = 32; o > 0; o >>= 1) mx = fmaxf(mx, __shfl_xor(mx, o));
    float e = EXP2F((logit - mx) * 1.44269504f);   // masked lanes -> 0
    float s = e;
#pragma unroll
    for (int o = 32; o > 0; o >>= 1) s += __shfl_xor(s, o);
    at4[lane][wid] = e * RCPF(s);
    __syncthreads();

    // ---- phase 2: wave wid covers u32 range [56*wid, +56), 4 n's ----
    int l56 = (lane < 56) ? lane : 55;
    int k   = wid * 56 + l56;                  // u32 index in row of 224
    const u32* lfb32 = (const u32*)(lf_bf + (size_t)b * HL_ * NEWS_DIM);
    float q00 = 0.f, q01 = 0.f, q10 = 0.f, q11 = 0.f;
    float q20 = 0.f, q21 = 0.f, q30 = 0.f, q31 = 0.f;
    for (int h = 0; h < HL_; h++) {
        float4 av = *(const float4*)at4[h];    // LDS broadcast, 4 attn vals
        u32 v = lfb32[h * (NEWS_DIM / 2) + k];
        float f0 = bf2f((u16)v), f1 = bf2f((u16)(v >> 16));
        q00 = fmaf(av.x, f0, q00);  q01 = fmaf(av.x, f1, q01);
        q10 = fmaf(av.y, f0, q10);  q11 = fmaf(av.y, f1, q11);
        q20 = fmaf(av.z, f0, q20);  q21 = fmaf(av.z, f1, q21);
        q30 = fmaf(av.w, f0, q30);  q31 = fmaf(av.w, f1, q31);
    }
    if (lane < 56) {
        float* o0 = out + (size_t)g0 * NEWS_DIM + 2 * k;
        *(float2*)(o0)                = make_float2(q00, q01);
        *(float2*)(o0 + NEWS_DIM)     = make_float2(q10, q11);
        *(float2*)(o0 + 2 * NEWS_DIM) = make_float2(q20, q21);
        *(float2*)(o0 + 3 * NEWS_DIM) = make_float2(q30, q31);
    }
}

extern "C" void kernel_launch(void* const* d_in, const int* in_sizes, int n_in,
                              void* d_out, int out_size, void* d_ws, size_t ws_size,
                              hipStream_t stream) {
    const float* logv  = (const float*)d_in[0];  // (64,50,384) f32
    const int*   lmask = (const int*)d_in[1];    // (64,50) i32
    const float* newsv = (const float*)d_in[2];  // (64,64,384) f32
    const float* pos   = (const float*)d_in[3];  // (100,64) f32; row 0 == 0
    const float* W1    = (const float*)d_in[4];  // (256,896) f32
    const float* b1    = (const float*)d_in[5];  // (256,) f32
    const float* w2    = (const float*)d_in[6];  // (1,256) f32
    // b2 unused (softmax-invariant shift)

    float* out = (float*)d_out;                  // [user_log | nf], f32
    float* nf  = out + (size_t)B_ * NN_ * NEWS_DIM;

    // d_ws ~256 MiB. Byte offsets, 16B aligned:
    char* ws = (char*)d_ws;
    u16*   lf_bf = (u16*)(ws + 0);               // 3200x448 bf16  (2,867,200 B)
    u16*   Wbf   = (u16*)(ws + 2867200);         // 256x896 bf16   (458,752 B)
    u16*   nv_bf = (u16*)(ws + 3325952);         // 4096x384 bf16  (3,145,728 B)
    float* pn    = (float*)(ws + 6471680);       // 4096x256 f32   (4,194,304 B)
    float* plT   = (float*)(ws + 10665984);      // 64x256x50 f32  (3,276,800 B)

    prep_k    <<<3416, 256, 0, stream>>>(W1, newsv, logv, pos,
                                         Wbf, nv_bf, lf_bf, nf);
    gemm_k    <<<1824, 64, 0, stream>>>(nv_bf, lf_bf, Wbf, b1, pn, plT);
    attn_out_k<<<1024, 256, 0, stream>>>(pn, plT, w2, lmask, lf_bf, out);
}